// Round 9
// baseline (341.771 us; speedup 1.0000x reference)
//
#include <hip/hip_runtime.h>
#include <hip/hip_bf16.h>

#define IN_DIM  128
#define HID_DIM 128
#define OUT_DIM 64

typedef unsigned short ushort_t;
struct ushort4_t { ushort_t x, y, z, w; };
typedef __attribute__((ext_vector_type(8))) short bf16x8;   // 8 bf16 (4 VGPRs)
typedef __attribute__((ext_vector_type(4))) float f32x4;    // MFMA acc

__device__ __forceinline__ float bf2f(ushort_t u) {
    return __uint_as_float(((unsigned int)u) << 16);
}
__device__ __forceinline__ short f2bf_s(float v) {
    __hip_bfloat16 t = __float2bfloat16(v);
    return *(short*)&t;
}
__device__ __forceinline__ unsigned int pack2(float a, float b) {
    return ((unsigned int)(ushort_t)f2bf_s(b) << 16) | (ushort_t)f2bf_s(a);
}

// ---------------- FUSED: gemm1 (odd blocks) || count+rank (even blocks) ----------------
// count role is device-atomic-throughput-bound (~24G/s HW ceiling: insensitive to grid size,
// collisions [r6], per-thread depth [r8]) and hides the whole GEMM for free.
__global__ __launch_bounds__(256, 2) void fused_gemm1_count(
        const float* __restrict__ x, const float* __restrict__ W,
        unsigned int* __restrict__ h,
        const int* __restrict__ dst, int* __restrict__ cnt, int* __restrict__ rank,
        int N, int E, int NT) {
    const int bid = blockIdx.x;
    const int tid = threadIdx.x;

    if (bid & 1) {
        // ---- GEMM1 role ----
        const int lane = tid & 63;
        const int m    = lane & 15;
        const int quad = lane >> 4;
        const int gw   = (bid >> 1) * 4 + (tid >> 6);
        const int NW   = 1024;                  // 256 blocks x 4 waves

        bf16x8 a[8][4];                         // 8 col-tiles x 4 k-chunks
        #pragma unroll
        for (int ct = 0; ct < 8; ++ct)
            #pragma unroll
            for (int kc = 0; kc < 4; ++kc)
                #pragma unroll
                for (int j = 0; j < 8; ++j)
                    a[ct][kc][j] = f2bf_s(W[(size_t)(kc * 32 + quad * 8 + j) * HID_DIM + ct * 16 + m]);

        for (int t = gw; t < NT; t += NW) {
            const int n0 = t * 16;
            int node = n0 + m; if (node >= N) node = N - 1;
            const float* xr = x + (size_t)node * IN_DIM + quad * 8;
            f32x4 acc[8];
            #pragma unroll
            for (int ct = 0; ct < 8; ++ct) acc[ct] = (f32x4){0.f, 0.f, 0.f, 0.f};
            #pragma unroll
            for (int kc = 0; kc < 4; ++kc) {
                const float4 v0 = *(const float4*)(xr + kc * 32);
                const float4 v1 = *(const float4*)(xr + kc * 32 + 4);
                bf16x8 b;
                b[0] = f2bf_s(v0.x); b[1] = f2bf_s(v0.y); b[2] = f2bf_s(v0.z); b[3] = f2bf_s(v0.w);
                b[4] = f2bf_s(v1.x); b[5] = f2bf_s(v1.y); b[6] = f2bf_s(v1.z); b[7] = f2bf_s(v1.w);
                #pragma unroll
                for (int ct = 0; ct < 8; ++ct)
                    acc[ct] = __builtin_amdgcn_mfma_f32_16x16x32_bf16(a[ct][kc], b, acc[ct], 0, 0, 0);
            }
            if (n0 + m < N) {
                unsigned int* o = h + (size_t)(n0 + m) * (HID_DIM / 2) + quad * 2;
                #pragma unroll
                for (int ct = 0; ct < 8; ++ct) {
                    uint2 pv;
                    pv.x = pack2(acc[ct][0], acc[ct][1]);
                    pv.y = pack2(acc[ct][2], acc[ct][3]);
                    *(uint2*)(o + ct * 8) = pv;
                }
            }
        }
    } else {
        // ---- count + rank role ----
        const int ct = (bid >> 1) * 256 + tid;
        const int CT = 256 * 256;
        const int nq = E >> 2;
        const int4* d4 = (const int4*)dst;
        for (int q = ct; q < nq; q += CT) {
            const int4 d = d4[q];
            int4 r;
            r.x = atomicAdd(&cnt[d.x], 1);
            r.y = atomicAdd(&cnt[d.y], 1);
            r.z = atomicAdd(&cnt[d.z], 1);
            r.w = atomicAdd(&cnt[d.w], 1);
            ((int4*)rank)[q] = r;
        }
        for (int e = (nq << 2) + ct; e < E; e += CT)
            rank[e] = atomicAdd(&cnt[dst[e]], 1);
    }
}

// ---------------- scan_fused: dinv + row_start + {0,0} pad records, ONE launch ----------------
// Each block re-derives its global offset by summing all preceding padded counts directly
// (<=392KB reads/block, S=49 blocks, all parallel) -> no bsum array, no second launch.
__global__ void scan_fused(const int* __restrict__ cnt, float* __restrict__ dinv,
                           int* __restrict__ row_start, int2* __restrict__ pack, int N) {
    __shared__ int wsum[4];
    __shared__ int sh_off;
    const int t = threadIdx.x;
    const int base0 = blockIdx.x * 2048;

    // global offset = sum of padded counts over [0, base0)
    int pre = 0;
    for (int i = t * 4; i < base0; i += 1024) {
        const int4 c4 = *(const int4*)(cnt + i);
        pre += ((c4.x + 3) & ~3) + ((c4.y + 3) & ~3) + ((c4.z + 3) & ~3) + ((c4.w + 3) & ~3);
    }
    #pragma unroll
    for (int off = 32; off > 0; off >>= 1) pre += __shfl_down(pre, off);
    const int lane = t & 63, w = t >> 6;
    if (lane == 0) wsum[w] = pre;
    __syncthreads();
    if (t == 0) sh_off = wsum[0] + wsum[1] + wsum[2] + wsum[3];
    __syncthreads();

    // local counts, dinv, padded values
    const int base = base0 + t * 8;
    int c[8], v[8];
    #pragma unroll
    for (int i = 0; i < 8; ++i) {
        c[i] = (base + i < N) ? cnt[base + i] : 0;
        v[i] = (c[i] + 3) & ~3;
        if (base + i < N) dinv[base + i] = rsqrtf((float)(c[i] + 1));   // +1 self loop
    }
    int s = v[0] + v[1] + v[2] + v[3] + v[4] + v[5] + v[6] + v[7];
    int incl = s;
    #pragma unroll
    for (int off = 1; off < 64; off <<= 1) {
        int u = __shfl_up(incl, off);
        if (lane >= off) incl += u;
    }
    if (lane == 63) wsum[w] = incl;
    __syncthreads();
    int woff = 0;
    for (int i = 0; i < w; ++i) woff += wsum[i];
    int run = sh_off + woff + (incl - s);
    const int2 zr = {0, 0};
    #pragma unroll
    for (int i = 0; i < 8; ++i) {
        if (base + i < N) {
            row_start[base + i] = run;
            for (int p = c[i]; p < v[i]; ++p) pack[run + p] = zr;   // pad: src=0, norm=0
            run += v[i];
        }
    }
}

// ---------------- fill packed CSR records {src, norm} (8B), no atomics, x4-vectorized ----------------
__global__ void fill_pack4(const int* __restrict__ src, const int* __restrict__ dst,
                           const int* __restrict__ rank, const int* __restrict__ row_start,
                           const float* __restrict__ dinv, int E, int2* __restrict__ pack) {
    const int q = blockIdx.x * blockDim.x + threadIdx.x;
    const int nq = E >> 2;
    if (q < nq) {
        const int4 s = ((const int4*)src)[q];
        const int4 d = ((const int4*)dst)[q];
        const int4 r = ((const int4*)rank)[q];
        int2 p;
        p.x = s.x; p.y = __float_as_int(dinv[s.x] * dinv[d.x]);
        pack[row_start[d.x] + r.x] = p;
        p.x = s.y; p.y = __float_as_int(dinv[s.y] * dinv[d.y]);
        pack[row_start[d.y] + r.y] = p;
        p.x = s.z; p.y = __float_as_int(dinv[s.z] * dinv[d.z]);
        pack[row_start[d.z] + r.z] = p;
        p.x = s.w; p.y = __float_as_int(dinv[s.w] * dinv[d.w]);
        pack[row_start[d.w] + r.w] = p;
    }
    if (q == 0) {   // tail (E not multiple of 4)
        for (int e = nq << 2; e < E; ++e) {
            int2 p;
            p.x = src[e]; p.y = __float_as_int(dinv[src[e]] * dinv[dst[e]]);
            pack[row_start[dst[e]] + rank[e]] = p;
        }
    }
}

// ---------------- GEMM2 (MFMA): h2[N,64](bf16) = agg_relu[N,128](bf16) @ W2[128,64] ----------------
__global__ __launch_bounds__(256) void gemm2_mfma(
        const ushort_t* __restrict__ agg,
        const float* __restrict__ W2, unsigned int* __restrict__ h2,
        int N, int NT, int NW) {
    const int tid  = threadIdx.x;
    const int lane = tid & 63;
    const int m    = lane & 15;
    const int quad = lane >> 4;
    const int gw   = blockIdx.x * 4 + (tid >> 6);

    bf16x8 a[4][4];                         // 4 col-tiles x 4 k-chunks
    #pragma unroll
    for (int ct = 0; ct < 4; ++ct)
        #pragma unroll
        for (int kc = 0; kc < 4; ++kc)
            #pragma unroll
            for (int j = 0; j < 8; ++j)
                a[ct][kc][j] = f2bf_s(W2[(size_t)(kc * 32 + quad * 8 + j) * OUT_DIM + ct * 16 + m]);

    for (int t = gw; t < NT; t += NW) {
        const int n0 = t * 16;
        int node = n0 + m; if (node >= N) node = N - 1;
        const ushort_t* ar = agg + (size_t)node * HID_DIM + quad * 8;
        f32x4 acc[4];
        #pragma unroll
        for (int ct = 0; ct < 4; ++ct) acc[ct] = (f32x4){0.f, 0.f, 0.f, 0.f};
        #pragma unroll
        for (int kc = 0; kc < 4; ++kc) {
            const bf16x8 b = *(const bf16x8*)(ar + kc * 32);
            #pragma unroll
            for (int ct = 0; ct < 4; ++ct)
                acc[ct] = __builtin_amdgcn_mfma_f32_16x16x32_bf16(a[ct][kc], b, acc[ct], 0, 0, 0);
        }
        if (n0 + m < N) {
            unsigned int* o = h2 + (size_t)(n0 + m) * (OUT_DIM / 2) + quad * 2;
            #pragma unroll
            for (int ct = 0; ct < 4; ++ct) {
                uint2 pv;
                pv.x = pack2(acc[ct][0], acc[ct][1]);
                pv.y = pack2(acc[ct][2], acc[ct][3]);
                *(uint2*)(o + ct * 8) = pv;
            }
        }
    }
}

// ---------------- gather: ONE WAVE PER NODE (zero intra-wave degree divergence) ----------------
// Lanes split into R = 256/D record-subgroups; each step processes R consecutive records of the
// SAME node; 1-2 step shfl_xor butterfly folds the R partial sums. Waves grid-stride over nodes
// independently -> work balanced at node granularity. Pad records {0,0} contribute nothing.
template<int D, bool BF16_OUT, bool RELU>
__global__ void gather_wave(const ushort_t* __restrict__ h, const int2* __restrict__ pack,
                            const int* __restrict__ row_start, const int* __restrict__ cnt,
                            const float* __restrict__ dinv, const float* __restrict__ bias,
                            int N, void* __restrict__ outv, int NWAVES) {
    const int lane = threadIdx.x & 63;
    const int gwid = (blockIdx.x * blockDim.x + threadIdx.x) >> 6;
    const int TPR  = D / 4;                 // lanes per record: 32 (D=128), 16 (D=64)
    const int R    = 64 / TPR;              // records per step: 2, 4
    const int f    = (lane & (TPR - 1)) * 4;
    const int rsub = lane / TPR;            // record-subgroup id 0..R-1

    for (int node = gwid; node < N; node += NWAVES) {
        const float dd = dinv[node];
        float4 acc = {0.f, 0.f, 0.f, 0.f};
        if (rsub == 0) {                    // self term + bias, added exactly once
            const ushort4_t self = *(const ushort4_t*)(h + (size_t)node * D + f);
            const float sn = dd * dd;
            const float4 bv = *(const float4*)(bias + f);
            acc.x = bf2f(self.x) * sn + bv.x;
            acc.y = bf2f(self.y) * sn + bv.y;
            acc.z = bf2f(self.z) * sn + bv.z;
            acc.w = bf2f(self.w) * sn + bv.w;
        }
        const int2* pk = pack + row_start[node];
        const int cpad = (cnt[node] + 3) & ~3;
        int e = 0;
        for (; e + 8 <= cpad; e += 8) {     // 8 records per iteration
            #pragma unroll
            for (int s = 0; s < 8; s += R) {
                const int2 pr = pk[e + s + rsub];
                const ushort4_t v = *(const ushort4_t*)(h + (size_t)pr.x * D + f);
                const float n = __int_as_float(pr.y);
                acc.x += bf2f(v.x) * n; acc.y += bf2f(v.y) * n;
                acc.z += bf2f(v.z) * n; acc.w += bf2f(v.w) * n;
            }
        }
        for (; e < cpad; e += 4) {          // remaining quads
            #pragma unroll
            for (int s = 0; s < 4; s += R) {
                const int2 pr = pk[e + s + rsub];
                const ushort4_t v = *(const ushort4_t*)(h + (size_t)pr.x * D + f);
                const float n = __int_as_float(pr.y);
                acc.x += bf2f(v.x) * n; acc.y += bf2f(v.y) * n;
                acc.z += bf2f(v.z) * n; acc.w += bf2f(v.w) * n;
            }
        }
        // fold the R record-subgroups (partner lanes have identical f)
        #pragma unroll
        for (int off = TPR; off < 64; off <<= 1) {
            acc.x += __shfl_xor(acc.x, off);
            acc.y += __shfl_xor(acc.y, off);
            acc.z += __shfl_xor(acc.z, off);
            acc.w += __shfl_xor(acc.w, off);
        }
        if (rsub == 0) {
            if (RELU) {
                acc.x = fmaxf(acc.x, 0.f); acc.y = fmaxf(acc.y, 0.f);
                acc.z = fmaxf(acc.z, 0.f); acc.w = fmaxf(acc.w, 0.f);
            }
            if (BF16_OUT) {
                unsigned int* out = (unsigned int*)outv;
                uint2 pv;
                pv.x = pack2(acc.x, acc.y);
                pv.y = pack2(acc.z, acc.w);
                *(uint2*)(out + ((size_t)node * D + f) / 2) = pv;
            } else {
                float* out = (float*)outv;
                *(float4*)(out + (size_t)node * D + f) = acc;
            }
        }
    }
}

extern "C" void kernel_launch(void* const* d_in, const int* in_sizes, int n_in,
                              void* d_out, int out_size, void* d_ws, size_t ws_size,
                              hipStream_t stream) {
    const float* x   = (const float*)d_in[0];
    const int*   ei  = (const int*)  d_in[1];
    const float* W1  = (const float*)d_in[2];
    const float* b1  = (const float*)d_in[3];
    const float* W2  = (const float*)d_in[4];
    const float* b2  = (const float*)d_in[5];
    float* out = (float*)d_out;

    const int N = in_sizes[0] / IN_DIM;     // 100000
    const int E = in_sizes[1] / 2;          // 1600000
    const int* src = ei;                    // edge_index[0]
    const int* dst = ei + E;                // edge_index[1]

    // workspace layout (4B units):
    // dinv[N] | cnt[N] | row_start[N] | align | pack[E+4N] int2
    // | h1[N*64] u32 (bf16 h1, reused as h2) | agg1[N*64] u32 (bf16; rank aliases it)
    const int PACK_CAP = E + 4 * N;
    float* dinv      = (float*)d_ws;
    int*   cnt       = (int*)(dinv + N);
    int*   row_start = cnt + N;
    size_t off       = (size_t)(3 * N);
    off = (off + 3) & ~(size_t)3;           // 16B-align pack
    int2*  pack      = (int2*)((int*)d_ws + off);
    unsigned int* h1 = (unsigned int*)(pack + PACK_CAP);
    unsigned int* agg1 = h1 + (size_t)N * (HID_DIM / 2);
    int*   rank      = (int*)agg1;          // alive only until fill_pack (E <= N*64)
    unsigned int* h2 = h1;                  // reuse after gather128

    const int B = 256;
    const int S = (N + 2047) / 2048;        // scan blocks
    const int NT = (N + 15) / 16;           // 16-node MFMA tiles
    const int GB = 4096;                    // gather blocks (GB*4 waves, grid-stride)

    // 1) CSR counts + rank, fused with GEMM1 (independent work hides atomic throughput floor)
    hipMemsetAsync(cnt, 0, (size_t)N * sizeof(int), stream);
    fused_gemm1_count<<<512, 256, 0, stream>>>(x, W1, h1, dst, cnt, rank, N, E, NT);

    // 2) fused scan: dinv + row_start + pad records, single launch
    scan_fused<<<S, 256, 0, stream>>>(cnt, dinv, row_start, pack, N);

    // 3) fill packed CSR records {src, norm}
    fill_pack4<<<((E >> 2) + B - 1) / B, B, 0, stream>>>(src, dst, rank, row_start, dinv, E, pack);

    // 4) agg1 = relu(gather(h1) + b1)  (bf16 out; overwrites rank)
    gather_wave<HID_DIM, true, true><<<GB, 256, 0, stream>>>(
        (const ushort_t*)h1, pack, row_start, cnt, dinv, b1, N, (void*)agg1, GB * 4);

    // 5) h2 = agg1 @ W2  (bf16 out, MFMA, raw b-frag loads)
    gemm2_mfma<<<768, 256, 0, stream>>>(
        (const ushort_t*)agg1, W2, h2, N, NT, 768 * 4);

    // 6) out = b2 + gather(h2)  (f32 out)
    gather_wave<OUT_DIM, false, false><<<GB, 256, 0, stream>>>(
        (const ushort_t*)h2, pack, row_start, cnt, dinv, b2, N, (void*)out, GB * 4);
}